// Round 1
// baseline (776.274 us; speedup 1.0000x reference)
//
#include <hip/hip_runtime.h>
#include <stdint.h>

typedef unsigned int u32;
typedef unsigned long long u64;

#define NCLS 80
#define NBOX 22743
#define PREK 4096
#define BCAP 65536
#define NIMG 8
#define SCORE_TH 0.01f
#define IOU_TH 0.45f
#define TOPK 200

// ---- workspace layout (bytes) ----
// [0,           131072)  : hist  u32[8][4096]
// [131072,      131200)  : meta  int[8][4]  {B, T, wincnt, bcnt}
// [131328,      393472)  : winners  u64[8][4096]
// [393472,      4587776) : boundary u64[8][65536]
// [4587776,     7498880) : boxes float4[8][22743]
#define HIST_OFF 0
#define META_OFF 131072
#define WIN_OFF  131328
#define BND_OFF  393472
#define BOX_OFF  4587776
#define ZERO_BYTES 131200

__device__ __forceinline__ float sigmf(float x) { return 1.0f / (1.0f + expf(-x)); }

// window-offset for float-bit bins: s in (0.01,1] -> (bits>>14) in [61583, 65024]
#define BIN_BASE 61440u

// ---------------- decode + per-image histogram ----------------
__global__ void decode_hist_k(const float* __restrict__ in, float4* __restrict__ boxes,
                              u32* __restrict__ hist,
                              int W, int HW, int lvl_off, float stride,
                              float aw0, float ah0, float aw1, float ah1, float aw2, float ah2) {
  __shared__ u32 lh[4096];
  const int img = blockIdx.y;
  for (int i = threadIdx.x; i < 4096; i += blockDim.x) lh[i] = 0;
  __syncthreads();

  const int r = blockIdx.x * blockDim.x + threadIdx.x;
  const int total = 3 * HW;
  if (r < total) {
    const int a = r / HW, p = r - a * HW;
    const int y = p / W, x = p - y * W;
    const float* base = in + ((size_t)(img * 255 + a * 85)) * (size_t)HW + p;
    const float aw = (a == 0) ? aw0 : ((a == 1) ? aw1 : aw2);
    const float ah = (a == 0) ? ah0 : ((a == 1) ? ah1 : ah2);
    const float x0 = base[0];
    const float x1 = base[(size_t)HW];
    const float x2 = base[2 * (size_t)HW];
    const float x3 = base[3 * (size_t)HW];
    const float x4 = base[4 * (size_t)HW];
    const float px = sigmf(x0) + (float)x;
    const float py = sigmf(x1) + (float)y;
    const float pw = expf(x2) * aw;
    const float ph = expf(x3) * ah;
    const float conf = sigmf(x4);
    const float cx = px * stride, cy = py * stride, bw = pw * stride, bh = ph * stride;
    float4 bb = make_float4(cx - bw * 0.5f, cy - bh * 0.5f, cx + bw * 0.5f, cy + bh * 0.5f);
    boxes[(size_t)img * NBOX + lvl_off + r] = bb;

    if (conf > SCORE_TH) {  // s = conf*sig <= conf, so conf<=th => no score passes
      for (int c = 0; c < NCLS; ++c) {
        float s = conf * sigmf(base[(size_t)(5 + c) * HW]);
        if (s > SCORE_TH) {
          u32 bin = (__float_as_uint(s) >> 14) - BIN_BASE;  // in [143, 3584]
          atomicAdd(&lh[bin], 1u);
        }
      }
    }
  }
  __syncthreads();
  u32* gh = hist + (size_t)img * 4096;
  for (int i = threadIdx.x; i < 4096; i += blockDim.x) {
    u32 v = lh[i];
    if (v) atomicAdd(&gh[i], v);
  }
}

// ---------------- find boundary bin B and residual T ----------------
__global__ void scan_k(const u32* __restrict__ hist, int* __restrict__ meta) {
  const int img = blockIdx.x;
  const u32* h = hist + (size_t)img * 4096;
  __shared__ u32 lsum[256];
  __shared__ u32 above[256];
  __shared__ u32 s_total;
  const int t = threadIdx.x;
  u32 s = 0;
  for (int j = 0; j < 16; ++j) s += h[t * 16 + j];
  lsum[t] = s;
  __syncthreads();
  if (t == 0) {
    u32 acc = 0;
    for (int i = 255; i >= 0; --i) { above[i] = acc; acc += lsum[i]; }
    s_total = acc;
  }
  __syncthreads();
  const u32 K = PREK;
  int* m = meta + img * 4;
  if (s_total < K) {
    if (t == 0) { m[0] = -1; m[1] = 0; }
  } else {
    if (above[t] < K && above[t] + lsum[t] >= K) {
      u32 cum = above[t];
      for (int j = 15; j >= 0; --j) {
        u32 hv = h[t * 16 + j];
        cum += hv;
        if (cum >= K) { m[0] = t * 16 + j; m[1] = (int)(K - (cum - hv)); break; }
      }
    }
  }
}

// ---------------- gather winners / boundary candidates ----------------
__global__ void gather_k(const float* __restrict__ in, int* __restrict__ meta,
                         u64* __restrict__ winners, u64* __restrict__ boundary,
                         int HW, int lvl_off) {
  const int img = blockIdx.y;
  const int r = blockIdx.x * blockDim.x + threadIdx.x;
  if (r >= 3 * HW) return;
  const int B = meta[img * 4 + 0];
  const int a = r / HW, p = r - a * HW;
  const float* base = in + ((size_t)(img * 255 + a * 85)) * (size_t)HW + p;
  const float conf = sigmf(base[4 * (size_t)HW]);
  if (conf <= SCORE_TH) return;
  const int boxg = lvl_off + r;
  u64* wl = winners + (size_t)img * PREK;
  u64* bl = boundary + (size_t)img * BCAP;
  for (int c = 0; c < NCLS; ++c) {
    float s = conf * sigmf(base[(size_t)(5 + c) * HW]);
    if (s > SCORE_TH) {
      u32 key = __float_as_uint(s);
      int wbin = (int)((key >> 14) - BIN_BASE);
      if (wbin > B) {
        int pos = atomicAdd(&meta[img * 4 + 2], 1);
        if (pos < PREK) wl[pos] = ((u64)key << 32) | (u64)(~(u32)(boxg * NCLS + c));
      } else if (wbin == B) {
        int pos = atomicAdd(&meta[img * 4 + 3], 1);
        if (pos < BCAP) bl[pos] = ((u64)key << 32) | (u64)(~(u32)(boxg * NCLS + c));
      }
    }
  }
}

// ---------------- resolve boundary bin: pick exactly T more ----------------
__global__ void resolve_k(const u64* __restrict__ boundary, int* __restrict__ meta,
                          u64* __restrict__ winners) {
  const int img = blockIdx.x;
  const int T = meta[img * 4 + 1];
  int bc = meta[img * 4 + 3];
  if (bc > BCAP) bc = BCAP;
  if (T <= 0 || bc <= 0) return;
  const u64* bnd = boundary + (size_t)img * BCAP;
  u64* wl = winners + (size_t)img * PREK;

  __shared__ u32 h2[16384];
  __shared__ u32 lsum[256];
  __shared__ u32 above[256];
  __shared__ u32 s_total;
  __shared__ int sB2, sT2;
  __shared__ u64 ties[512];
  __shared__ int tcnt;
  const int t = threadIdx.x;
  for (int i = t; i < 16384; i += 256) h2[i] = 0;
  if (t == 0) { tcnt = 0; sB2 = -1; sT2 = 0; }
  __syncthreads();
  for (int i = t; i < bc; i += 256) atomicAdd(&h2[(u32)(bnd[i] >> 32) & 0x3FFFu], 1u);
  __syncthreads();
  u32 s = 0;
  for (int j = 0; j < 64; ++j) s += h2[t * 64 + j];
  lsum[t] = s;
  __syncthreads();
  if (t == 0) {
    u32 acc = 0;
    for (int i = 255; i >= 0; --i) { above[i] = acc; acc += lsum[i]; }
    s_total = acc;
  }
  __syncthreads();
  if ((int)s_total > T) {
    if (above[t] < (u32)T && above[t] + lsum[t] >= (u32)T) {
      u32 cum = above[t];
      for (int j = 63; j >= 0; --j) {
        u32 hv = h2[t * 64 + j];
        cum += hv;
        if (cum >= (u32)T) { sB2 = t * 64 + j; sT2 = (int)((u32)T - (cum - hv)); break; }
      }
    }
  }
  __syncthreads();
  const int B2 = sB2, T2 = sT2;
  for (int i = t; i < bc; i += 256) {
    u64 e = bnd[i];
    int low = (int)((u32)(e >> 32) & 0x3FFFu);
    if (low > B2) {
      int pos = atomicAdd(&meta[img * 4 + 2], 1);
      if (pos < PREK) wl[pos] = e;
    } else if (low == B2) {
      int tp = atomicAdd(&tcnt, 1);
      if (tp < 512) ties[tp] = e;
    }
  }
  __syncthreads();
  if (t == 0 && T2 > 0) {
    int tc = tcnt < 512 ? tcnt : 512;
    for (int k = 0; k < T2 && k < tc; ++k) {
      int bi = -1; u64 bk = 0;
      for (int i = 0; i < tc; ++i)
        if (ties[i] > bk) { bk = ties[i]; bi = i; }  // same score => larger ~idx = smaller idx first
      if (bi < 0) break;
      ties[bi] = 0;
      int pos = atomicAdd(&meta[img * 4 + 2], 1);
      if (pos < PREK) wl[pos] = bk;
    }
  }
}

// ---------------- greedy class-aware NMS, 200 picks ----------------
__global__ __launch_bounds__(1024) void nms_k(const u64* __restrict__ winners,
                                              const int* __restrict__ meta,
                                              const float4* __restrict__ boxes,
                                              float* __restrict__ out) {
  const int img = blockIdx.x;
  __shared__ float4 s_ob[PREK];
  __shared__ float s_area[PREK];
  __shared__ u64 s_rk[16];
  __shared__ int s_rs[16];
  __shared__ u64 s_bk;
  __shared__ int s_bs;
  const int t = threadIdx.x;
  int wc = meta[img * 4 + 2];
  if (wc > PREK) wc = PREK;

  u64 key[4];
  for (int k = 0; k < 4; ++k) {
    int slot = t + k * 1024;
    if (slot < wc) {
      u64 e = winners[(size_t)img * PREK + slot];
      key[k] = e;
      u32 ridx = ~(u32)e;
      int c = ridx % NCLS;
      int bi = ridx / NCLS;
      float4 b = boxes[(size_t)img * NBOX + bi];
      float off = 4096.0f * (float)c;
      float4 ob = make_float4(b.x + off, b.y + off, b.z + off, b.w + off);
      s_ob[slot] = ob;
      s_area[slot] = (ob.z - ob.x) * (ob.w - ob.y);
    } else {
      key[k] = 0ull;
      s_ob[slot] = make_float4(0.f, 0.f, 0.f, 0.f);
      s_area[slot] = 0.f;
    }
  }
  float* orow = out + (size_t)img * (TOPK * 6);
  for (int i = t; i < TOPK * 6; i += 1024) orow[i] = 0.f;
  __syncthreads();

  const int lane = t & 63, wid = t >> 6;
  for (int it = 0; it < TOPK; ++it) {
    u64 bk = key[0]; int bsl = t;
    for (int k = 1; k < 4; ++k)
      if (key[k] > bk) { bk = key[k]; bsl = t + k * 1024; }
    for (int off = 32; off > 0; off >>= 1) {
      u64 ok = __shfl_down(bk, off);
      int os = __shfl_down(bsl, off);
      if (ok > bk) { bk = ok; bsl = os; }
    }
    if (lane == 0) { s_rk[wid] = bk; s_rs[wid] = bsl; }
    __syncthreads();
    if (wid == 0) {
      u64 k2 = (lane < 16) ? s_rk[lane] : 0ull;
      int s2 = (lane < 16) ? s_rs[lane] : 0;
      for (int off = 8; off > 0; off >>= 1) {
        u64 ok = __shfl_down(k2, off);
        int os = __shfl_down(s2, off);
        if (ok > k2) { k2 = ok; s2 = os; }
      }
      if (lane == 0) { s_bk = k2; s_bs = s2; }
    }
    __syncthreads();
    const u64 BK = s_bk;
    if (BK == 0ull) break;  // uniform: all remaining rows stay zero
    const int BS = s_bs;
    const float4 sb = s_ob[BS];
    const float sa = s_area[BS];
    if (t == 0) {
      float score = __uint_as_float((u32)(BK >> 32));
      u32 ridx = ~(u32)BK;
      int c = (int)(ridx % NCLS);
      float off = 4096.0f * (float)c;
      orow[it * 6 + 0] = sb.x - off;
      orow[it * 6 + 1] = sb.y - off;
      orow[it * 6 + 2] = sb.z - off;
      orow[it * 6 + 3] = sb.w - off;
      orow[it * 6 + 4] = (float)c;
      orow[it * 6 + 5] = score;
    }
    for (int k = 0; k < 4; ++k) {
      if (key[k] == 0ull) continue;
      int slot = t + k * 1024;
      float4 ob = s_ob[slot];
      float xx1 = fmaxf(sb.x, ob.x), yy1 = fmaxf(sb.y, ob.y);
      float xx2 = fminf(sb.z, ob.z), yy2 = fminf(sb.w, ob.w);
      float inter = fmaxf(xx2 - xx1, 0.f) * fmaxf(yy2 - yy1, 0.f);
      float iou = inter / (sa + s_area[slot] - inter + 1e-9f);  // ref op order
      if (iou > IOU_TH) key[k] = 0ull;
    }
  }
}

extern "C" void kernel_launch(void* const* d_in, const int* in_sizes, int n_in,
                              void* d_out, int out_size, void* d_ws, size_t ws_size,
                              hipStream_t stream) {
  const float* in0 = (const float*)d_in[0];
  const float* in1 = (const float*)d_in[5];
  const float* in2 = (const float*)d_in[10];
  char* ws = (char*)d_ws;
  u32* hist = (u32*)(ws + HIST_OFF);
  int* meta = (int*)(ws + META_OFF);
  u64* winners = (u64*)(ws + WIN_OFF);
  u64* boundary = (u64*)(ws + BND_OFF);
  float4* boxes = (float4*)(ws + BOX_OFF);
  float* out = (float*)d_out;

  hipMemsetAsync(d_ws, 0, ZERO_BYTES, stream);

  // level 0: 19x19, stride 32
  decode_hist_k<<<dim3(5, 8), 256, 0, stream>>>(in0, boxes, hist, 19, 361, 0, 32.f,
                                                3.625f, 2.8125f, 4.875f, 6.1875f, 11.65625f, 10.1875f);
  // level 1: 38x38, stride 16
  decode_hist_k<<<dim3(17, 8), 256, 0, stream>>>(in1, boxes, hist, 38, 1444, 1083, 16.f,
                                                 1.875f, 3.8125f, 3.875f, 2.8125f, 3.6875f, 7.4375f);
  // level 2: 76x76, stride 8
  decode_hist_k<<<dim3(68, 8), 256, 0, stream>>>(in2, boxes, hist, 76, 5776, 5415, 8.f,
                                                 1.25f, 1.625f, 2.f, 3.75f, 4.125f, 2.875f);

  scan_k<<<8, 256, 0, stream>>>(hist, meta);

  gather_k<<<dim3(5, 8), 256, 0, stream>>>(in0, meta, winners, boundary, 361, 0);
  gather_k<<<dim3(17, 8), 256, 0, stream>>>(in1, meta, winners, boundary, 1444, 1083);
  gather_k<<<dim3(68, 8), 256, 0, stream>>>(in2, meta, winners, boundary, 5776, 5415);

  resolve_k<<<8, 256, 0, stream>>>(boundary, meta, winners);

  nms_k<<<8, 1024, 0, stream>>>(winners, meta, boxes, out);
}

// Round 2
// 556.512 us; speedup vs baseline: 1.3949x; 1.3949x over previous
//
#include <hip/hip_runtime.h>
#include <stdint.h>

typedef unsigned int u32;
typedef unsigned long long u64;

#define NCLS 80
#define NBOX 22743
#define PREK 4096
#define BCAP 65536
#define NIMG 8
#define SCORE_TH 0.01f
#define IOU_TH 0.45f
#define TOPK 200

// ---- workspace layout (bytes) ----
// [0,           131072)  : hist  u32[8][4096]
// [131072,      131200)  : meta  int[8][4]  {B, T, wincnt, bcnt}
// [131328,      393472)  : winners  u64[8][4096]
// [393472,      4587776) : boundary u64[8][65536]
// [4587776,     7498880) : boxes float4[8][22743]
// [7498880,     7761024) : skey  u64[8][4096]   (sorted keys)
// [7761024,     8285312) : sobox float4[8][4096] (sorted offset boxes)
// [8285312,     8416384) : sarea float[8][4096]
#define HIST_OFF 0
#define META_OFF 131072
#define WIN_OFF  131328
#define BND_OFF  393472
#define BOX_OFF  4587776
#define SKEY_OFF 7498880
#define SOBOX_OFF 7761024
#define SAREA_OFF 8285312
#define ZERO_BYTES 131200

__device__ __forceinline__ float sigmf(float x) { return 1.0f / (1.0f + expf(-x)); }

// window-offset for float-bit bins: s in (0.01,1] -> (bits>>14) in [61583, 65024]
#define BIN_BASE 61440u

// ---------------- decode + per-image histogram ----------------
__global__ void decode_hist_k(const float* __restrict__ in, float4* __restrict__ boxes,
                              u32* __restrict__ hist,
                              int W, int HW, int lvl_off, float stride,
                              float aw0, float ah0, float aw1, float ah1, float aw2, float ah2) {
  __shared__ u32 lh[4096];
  const int img = blockIdx.y;
  for (int i = threadIdx.x; i < 4096; i += blockDim.x) lh[i] = 0;
  __syncthreads();

  const int r = blockIdx.x * blockDim.x + threadIdx.x;
  const int total = 3 * HW;
  if (r < total) {
    const int a = r / HW, p = r - a * HW;
    const int y = p / W, x = p - y * W;
    const float* base = in + ((size_t)(img * 255 + a * 85)) * (size_t)HW + p;
    const float aw = (a == 0) ? aw0 : ((a == 1) ? aw1 : aw2);
    const float ah = (a == 0) ? ah0 : ((a == 1) ? ah1 : ah2);
    const float x0 = base[0];
    const float x1 = base[(size_t)HW];
    const float x2 = base[2 * (size_t)HW];
    const float x3 = base[3 * (size_t)HW];
    const float x4 = base[4 * (size_t)HW];
    const float px = sigmf(x0) + (float)x;
    const float py = sigmf(x1) + (float)y;
    const float pw = expf(x2) * aw;
    const float ph = expf(x3) * ah;
    const float conf = sigmf(x4);
    const float cx = px * stride, cy = py * stride, bw = pw * stride, bh = ph * stride;
    float4 bb = make_float4(cx - bw * 0.5f, cy - bh * 0.5f, cx + bw * 0.5f, cy + bh * 0.5f);
    boxes[(size_t)img * NBOX + lvl_off + r] = bb;

    if (conf > SCORE_TH) {  // s = conf*sig <= conf, so conf<=th => no score passes
      for (int c = 0; c < NCLS; ++c) {
        float s = conf * sigmf(base[(size_t)(5 + c) * HW]);
        if (s > SCORE_TH) {
          u32 bin = (__float_as_uint(s) >> 14) - BIN_BASE;  // in [143, 3584]
          atomicAdd(&lh[bin], 1u);
        }
      }
    }
  }
  __syncthreads();
  u32* gh = hist + (size_t)img * 4096;
  for (int i = threadIdx.x; i < 4096; i += blockDim.x) {
    u32 v = lh[i];
    if (v) atomicAdd(&gh[i], v);
  }
}

// ---------------- find boundary bin B and residual T ----------------
__global__ void scan_k(const u32* __restrict__ hist, int* __restrict__ meta) {
  const int img = blockIdx.x;
  const u32* h = hist + (size_t)img * 4096;
  __shared__ u32 lsum[256];
  __shared__ u32 above[256];
  __shared__ u32 s_total;
  const int t = threadIdx.x;
  u32 s = 0;
  for (int j = 0; j < 16; ++j) s += h[t * 16 + j];
  lsum[t] = s;
  __syncthreads();
  if (t == 0) {
    u32 acc = 0;
    for (int i = 255; i >= 0; --i) { above[i] = acc; acc += lsum[i]; }
    s_total = acc;
  }
  __syncthreads();
  const u32 K = PREK;
  int* m = meta + img * 4;
  if (s_total < K) {
    if (t == 0) { m[0] = -1; m[1] = 0; }
  } else {
    if (above[t] < K && above[t] + lsum[t] >= K) {
      u32 cum = above[t];
      for (int j = 15; j >= 0; --j) {
        u32 hv = h[t * 16 + j];
        cum += hv;
        if (cum >= K) { m[0] = t * 16 + j; m[1] = (int)(K - (cum - hv)); break; }
      }
    }
  }
}

// ---------------- gather winners / boundary candidates ----------------
__global__ void gather_k(const float* __restrict__ in, int* __restrict__ meta,
                         u64* __restrict__ winners, u64* __restrict__ boundary,
                         int HW, int lvl_off) {
  const int img = blockIdx.y;
  const int r = blockIdx.x * blockDim.x + threadIdx.x;
  if (r >= 3 * HW) return;
  const int B = meta[img * 4 + 0];
  const int a = r / HW, p = r - a * HW;
  const float* base = in + ((size_t)(img * 255 + a * 85)) * (size_t)HW + p;
  const float conf = sigmf(base[4 * (size_t)HW]);
  if (conf <= SCORE_TH) return;
  const int boxg = lvl_off + r;
  u64* wl = winners + (size_t)img * PREK;
  u64* bl = boundary + (size_t)img * BCAP;
  for (int c = 0; c < NCLS; ++c) {
    float s = conf * sigmf(base[(size_t)(5 + c) * HW]);
    if (s > SCORE_TH) {
      u32 key = __float_as_uint(s);
      int wbin = (int)((key >> 14) - BIN_BASE);
      if (wbin > B) {
        int pos = atomicAdd(&meta[img * 4 + 2], 1);
        if (pos < PREK) wl[pos] = ((u64)key << 32) | (u64)(~(u32)(boxg * NCLS + c));
      } else if (wbin == B) {
        int pos = atomicAdd(&meta[img * 4 + 3], 1);
        if (pos < BCAP) bl[pos] = ((u64)key << 32) | (u64)(~(u32)(boxg * NCLS + c));
      }
    }
  }
}

// ---------------- resolve boundary bin: pick exactly T more ----------------
__global__ void resolve_k(const u64* __restrict__ boundary, int* __restrict__ meta,
                          u64* __restrict__ winners) {
  const int img = blockIdx.x;
  const int T = meta[img * 4 + 1];
  int bc = meta[img * 4 + 3];
  if (bc > BCAP) bc = BCAP;
  if (T <= 0 || bc <= 0) return;
  const u64* bnd = boundary + (size_t)img * BCAP;
  u64* wl = winners + (size_t)img * PREK;

  __shared__ u32 h2[16384];
  __shared__ u32 lsum[256];
  __shared__ u32 above[256];
  __shared__ u32 s_total;
  __shared__ int sB2, sT2;
  __shared__ u64 ties[512];
  __shared__ int tcnt;
  const int t = threadIdx.x;
  for (int i = t; i < 16384; i += 256) h2[i] = 0;
  if (t == 0) { tcnt = 0; sB2 = -1; sT2 = 0; }
  __syncthreads();
  for (int i = t; i < bc; i += 256) atomicAdd(&h2[(u32)(bnd[i] >> 32) & 0x3FFFu], 1u);
  __syncthreads();
  u32 s = 0;
  for (int j = 0; j < 64; ++j) s += h2[t * 64 + j];
  lsum[t] = s;
  __syncthreads();
  if (t == 0) {
    u32 acc = 0;
    for (int i = 255; i >= 0; --i) { above[i] = acc; acc += lsum[i]; }
    s_total = acc;
  }
  __syncthreads();
  if ((int)s_total > T) {
    if (above[t] < (u32)T && above[t] + lsum[t] >= (u32)T) {
      u32 cum = above[t];
      for (int j = 63; j >= 0; --j) {
        u32 hv = h2[t * 64 + j];
        cum += hv;
        if (cum >= (u32)T) { sB2 = t * 64 + j; sT2 = (int)((u32)T - (cum - hv)); break; }
      }
    }
  }
  __syncthreads();
  const int B2 = sB2, T2 = sT2;
  for (int i = t; i < bc; i += 256) {
    u64 e = bnd[i];
    int low = (int)((u32)(e >> 32) & 0x3FFFu);
    if (low > B2) {
      int pos = atomicAdd(&meta[img * 4 + 2], 1);
      if (pos < PREK) wl[pos] = e;
    } else if (low == B2) {
      int tp = atomicAdd(&tcnt, 1);
      if (tp < 512) ties[tp] = e;
    }
  }
  __syncthreads();
  if (t == 0 && T2 > 0) {
    int tc = tcnt < 512 ? tcnt : 512;
    for (int k = 0; k < T2 && k < tc; ++k) {
      int bi = -1; u64 bk = 0;
      for (int i = 0; i < tc; ++i)
        if (ties[i] > bk) { bk = ties[i]; bi = i; }  // same score => larger ~idx = smaller idx first
      if (bi < 0) break;
      ties[bi] = 0;
      int pos = atomicAdd(&meta[img * 4 + 2], 1);
      if (pos < PREK) wl[pos] = bk;
    }
  }
}

// ---------------- exact sort by rank (keys unique) ----------------
__global__ __launch_bounds__(256) void rank_k(const u64* __restrict__ winners,
                                              const int* __restrict__ meta,
                                              const float4* __restrict__ boxes,
                                              u64* __restrict__ skey,
                                              float4* __restrict__ sobox,
                                              float* __restrict__ sarea) {
  __shared__ u64 lk[PREK];
  const int img = blockIdx.y;
  const int t = threadIdx.x;
  int wc = meta[img * 4 + 2]; if (wc > PREK) wc = PREK;
  for (int i = t; i < PREK; i += 256)
    lk[i] = (i < wc) ? winners[(size_t)img * PREK + i] : (u64)(~(u32)i);  // distinct pads, below all real keys
  __syncthreads();
  const int i = blockIdx.x * 256 + t;
  const u64 ki = lk[i];
  int rank = 0;
#pragma unroll 8
  for (int j = 0; j < PREK; ++j) rank += (lk[j] > ki) ? 1 : 0;
  skey[(size_t)img * PREK + rank] = ki;
  if (i < wc) {
    u32 ridx = ~(u32)ki;
    int c = (int)(ridx % NCLS);
    int bi = (int)(ridx / NCLS);
    float4 b = boxes[(size_t)img * NBOX + bi];
    float off = 4096.0f * (float)c;
    float4 ob = make_float4(b.x + off, b.y + off, b.z + off, b.w + off);
    sobox[(size_t)img * PREK + rank] = ob;
    sarea[(size_t)img * PREK + rank] = (ob.z - ob.x) * (ob.w - ob.y);
  } else {
    sobox[(size_t)img * PREK + rank] = make_float4(0.f, 0.f, 0.f, 0.f);
    sarea[(size_t)img * PREK + rank] = 0.f;
  }
}

// ---------------- sorted-scan greedy NMS: one wave per image ----------------
__global__ __launch_bounds__(64) void scan_nms_k(const u64* __restrict__ skey,
                                                 const float4* __restrict__ sobox,
                                                 const float* __restrict__ sarea,
                                                 float* __restrict__ out) {
  __shared__ float4 selb[TOPK];
  __shared__ float sela[TOPK];
  const int img = blockIdx.x;
  const int lane = threadIdx.x;
  float* orow = out + (size_t)img * (TOPK * 6);
  for (int i = lane; i < TOPK * 6; i += 64) orow[i] = 0.f;
  const u64* K = skey + (size_t)img * PREK;
  const float4* B = sobox + (size_t)img * PREK;
  const float* A = sarea + (size_t)img * PREK;
  int nsel = 0;
  for (int chunk = 0; chunk < PREK / 64 && nsel < TOPK; ++chunk) {
    const int j = chunk * 64 + lane;
    const u64 kj = K[j];
    const float score = __uint_as_float((u32)(kj >> 32));
    bool alive = (score > SCORE_TH);
    if (__ballot(alive) == 0ull) break;   // sorted: nothing below passes either
    const float4 ob = B[j];
    const float ar = A[j];
    // phase 1: test against previously selected boxes (broadcast LDS reads)
    for (int s = 0; s < nsel; ++s) {
      if ((s & 15) == 0 && __ballot(alive) == 0ull) break;
      const float4 sb = selb[s];
      const float sa = sela[s];
      if (alive) {
        float xx1 = fmaxf(sb.x, ob.x), yy1 = fmaxf(sb.y, ob.y);
        float xx2 = fminf(sb.z, ob.z), yy2 = fminf(sb.w, ob.w);
        float inter = fmaxf(xx2 - xx1, 0.f) * fmaxf(yy2 - yy1, 0.f);
        float iou = inter / (sa + ar - inter + 1e-9f);  // ref op order: sel_area + cand_area
        if (iou > IOU_TH) alive = false;
      }
    }
    // phase 2: serial in-chunk resolution (ascending rank = ref selection order)
    u64 am = __ballot(alive);
    while (am != 0ull && nsel < TOPK) {
      const int b = __builtin_ctzll(am);
      const float bx = __shfl(ob.x, b), by = __shfl(ob.y, b);
      const float bz = __shfl(ob.z, b), bw = __shfl(ob.w, b);
      const float ba = __shfl(ar, b);
      if (lane == b) {
        selb[nsel] = ob; sela[nsel] = ar;
        u32 ridx = ~(u32)kj;
        int c = (int)(ridx % NCLS);
        float off = 4096.0f * (float)c;
        orow[nsel * 6 + 0] = ob.x - off;
        orow[nsel * 6 + 1] = ob.y - off;
        orow[nsel * 6 + 2] = ob.z - off;
        orow[nsel * 6 + 3] = ob.w - off;
        orow[nsel * 6 + 4] = (float)c;
        orow[nsel * 6 + 5] = score;
        alive = false;
      }
      nsel++;
      if (alive && lane > b) {
        float xx1 = fmaxf(bx, ob.x), yy1 = fmaxf(by, ob.y);
        float xx2 = fminf(bz, ob.z), yy2 = fminf(bw, ob.w);
        float inter = fmaxf(xx2 - xx1, 0.f) * fmaxf(yy2 - yy1, 0.f);
        float iou = inter / (ba + ar - inter + 1e-9f);
        if (iou > IOU_TH) alive = false;
      }
      am = __ballot(alive);
    }
  }
}

extern "C" void kernel_launch(void* const* d_in, const int* in_sizes, int n_in,
                              void* d_out, int out_size, void* d_ws, size_t ws_size,
                              hipStream_t stream) {
  const float* in0 = (const float*)d_in[0];
  const float* in1 = (const float*)d_in[5];
  const float* in2 = (const float*)d_in[10];
  char* ws = (char*)d_ws;
  u32* hist = (u32*)(ws + HIST_OFF);
  int* meta = (int*)(ws + META_OFF);
  u64* winners = (u64*)(ws + WIN_OFF);
  u64* boundary = (u64*)(ws + BND_OFF);
  float4* boxes = (float4*)(ws + BOX_OFF);
  u64* skey = (u64*)(ws + SKEY_OFF);
  float4* sobox = (float4*)(ws + SOBOX_OFF);
  float* sarea = (float*)(ws + SAREA_OFF);
  float* out = (float*)d_out;

  hipMemsetAsync(d_ws, 0, ZERO_BYTES, stream);

  // level 0: 19x19, stride 32
  decode_hist_k<<<dim3(5, 8), 256, 0, stream>>>(in0, boxes, hist, 19, 361, 0, 32.f,
                                                3.625f, 2.8125f, 4.875f, 6.1875f, 11.65625f, 10.1875f);
  // level 1: 38x38, stride 16
  decode_hist_k<<<dim3(17, 8), 256, 0, stream>>>(in1, boxes, hist, 38, 1444, 1083, 16.f,
                                                 1.875f, 3.8125f, 3.875f, 2.8125f, 3.6875f, 7.4375f);
  // level 2: 76x76, stride 8
  decode_hist_k<<<dim3(68, 8), 256, 0, stream>>>(in2, boxes, hist, 76, 5776, 5415, 8.f,
                                                 1.25f, 1.625f, 2.f, 3.75f, 4.125f, 2.875f);

  scan_k<<<8, 256, 0, stream>>>(hist, meta);

  gather_k<<<dim3(5, 8), 256, 0, stream>>>(in0, meta, winners, boundary, 361, 0);
  gather_k<<<dim3(17, 8), 256, 0, stream>>>(in1, meta, winners, boundary, 1444, 1083);
  gather_k<<<dim3(68, 8), 256, 0, stream>>>(in2, meta, winners, boundary, 5776, 5415);

  resolve_k<<<8, 256, 0, stream>>>(boundary, meta, winners);

  rank_k<<<dim3(16, 8), 256, 0, stream>>>(winners, meta, boxes, skey, sobox, sarea);
  scan_nms_k<<<8, 64, 0, stream>>>(skey, sobox, sarea, out);
}